// Round 2
// baseline (364.373 us; speedup 1.0000x reference)
//
#include <hip/hip_runtime.h>

// CTC forward loss, linear-space (scaled) forward algorithm, fp64 alpha.
// B=256, T=1024, C=256 (blank=255), L=128, S=2L+1=257.
// One 64-lane wave per batch element. Lane l holds extended states
// 4l+1..4l+4 in r1..r4 (fp64); state 0 (pure blank chain) replicated in a0.
// Cross-lane s-1/s-2 neighbors via DPP WAVE_SHR1 on both 32-bit halves.
// fp64 gives ~744 nats of dynamic range below the running scale — fp32's
// ~100 nats truncated genuinely-contributing low states (round-1: absmax 40).
// Frame probabilities prefetched DPF steps ahead in fp32 registers.

#define T_DIM 1024
#define C_DIM 256
#define L_DIM 128
#define DPF   16
#define EPSF  1e-7f
#define LN2D  0.69314718055994530942

// shuffle-up-by-1 across the 64-lane wave (both halves); lane 0 gets `old`.
__device__ __forceinline__ double dpp_shr1_f64(double old, double v) {
    int rlo = __builtin_amdgcn_update_dpp(__double2loint(old), __double2loint(v),
                                          0x138 /*WAVE_SHR1*/, 0xF, 0xF, false);
    int rhi = __builtin_amdgcn_update_dpp(__double2hiint(old), __double2hiint(v),
                                          0x138 /*WAVE_SHR1*/, 0xF, 0xF, false);
    return __hiloint2double(rhi, rlo);
}

// wave-wide int max (inputs >= 0), result broadcast via readlane(63).
__device__ __forceinline__ int wave_imax_all(int v) {
#define STAGE(CTRL) { int t_ = __builtin_amdgcn_update_dpp(v, v, CTRL, 0xF, 0xF, false); \
                      v = v > t_ ? v : t_; }
    STAGE(0x111)  // row_shr:1
    STAGE(0x112)  // row_shr:2
    STAGE(0x114)  // row_shr:4
    STAGE(0x118)  // row_shr:8
    STAGE(0x142)  // row_bcast:15
    STAGE(0x143)  // row_bcast:31
#undef STAGE
    return __builtin_amdgcn_readlane(v, 63);
}

__device__ __forceinline__ void ctc_step(double p0, double p1, double pB,
                                         double k1, double k3, double& a0,
                                         double& r1, double& r2, double& r3, double& r4) {
    // neighbors from previous lane: A[4l] = prev.r4, A[4l-1] = prev.r3
    double sA4 = dpp_shr1_f64(a0,  r4);   // lane0 <- state 0 (a0)
    double sA3 = dpp_shr1_f64(0.0, r3);   // lane0 <- 0 (state -1)
    double n1 = p0 * fma(k1, sA3, r1 + sA4);  // odd state 4l+1 (label 2l)
    double n2 = pB * (r2 + r1);               // blank state 4l+2
    double n3 = p1 * fma(k3, r1, r3 + r2);    // odd state 4l+3 (label 2l+1)
    double n4 = pB * (r4 + r3);               // blank state 4l+4
    a0 *= pB;                                 // state 0: blank self-loop only
    r1 = n1; r2 = n2; r3 = n3; r4 = n4;
}

__global__ __launch_bounds__(64, 1)
void ctc_fwd(const int* __restrict__ labels, const float* __restrict__ ypred,
             float* __restrict__ out) {
    const int b = blockIdx.x;
    const int l = threadIdx.x;  // lane 0..63
    const float* Yb = ypred + (size_t)b * (T_DIM * C_DIM);

    // labels 2l, 2l+1 (L=128 = exactly 2 per lane)
    const int2 lab = ((const int2*)(labels + b * L_DIM))[l];
    const int c0 = lab.x, c1 = lab.y;
    // blank class index in a VGPR (defeat scalarization -> keep on vmem path)
    int cB;
    asm("v_mov_b32 %0, 255" : "=v"(cB));

    const int labprev = __shfl_up(c1, 1, 64);
    const double k1 = (l == 0 || labprev == c0) ? 0.0 : 1.0;  // skip into 4l+1
    const double k3 = (c1 == c0) ? 0.0 : 1.0;                 // skip into 4l+3

    // t = 0 init: alpha0[0] = p'(0,blank), alpha0[1] = p'(0,label0)
    double a0 = (double)(Yb[cB] + EPSF);  // uniform across lanes
    double r1 = (l == 0) ? (double)(Yb[c0] + EPSF) : 0.0;
    double r2 = 0.0, r3 = 0.0, r4 = 0.0;
    int e2acc = 0;  // exact log2 scale accumulator

    // register prefetch pipeline: frame t lives in slot (t-1) & 15
    float f0[DPF], f1[DPF], fB[DPF];
#pragma unroll
    for (int d = 0; d < DPF; ++d) {
        const float* p = Yb + (size_t)(1 + d) * C_DIM;
        f0[d] = p[c0]; f1[d] = p[c1]; fB[d] = p[cB];
    }

    // main loop: 63 chunks of 16 steps cover t = 1..1008
    for (int tb = 1; tb <= 993; tb += 16) {
#pragma unroll
        for (int d = 0; d < 16; ++d) {
            ctc_step((double)(f0[d] + EPSF), (double)(f1[d] + EPSF),
                     (double)(fB[d] + EPSF), k1, k3, a0, r1, r2, r3, r4);
            int tn = tb + d + DPF;
            tn = tn > T_DIM - 1 ? T_DIM - 1 : tn;  // clamp (dup loads, unused)
            const float* p = Yb + (size_t)tn * C_DIM;
            f0[d] = p[c0]; f1[d] = p[c1]; fB[d] = p[cB];
        }
        // rescale by exact power of two. Positive doubles order by hi word,
        // and we only need the exponent -> int max on hi words.
        int h = __double2hiint(r1);
        int t_;
        t_ = __double2hiint(r2); h = h > t_ ? h : t_;
        t_ = __double2hiint(r3); h = h > t_ ? h : t_;
        t_ = __double2hiint(r4); h = h > t_ ? h : t_;
        t_ = __double2hiint(a0); h = h > t_ ? h : t_;
        int H = wave_imax_all(h);
        int k = (H >> 20) - 1023;               // exponent of wave max
        double s = __hiloint2double((1023 - k) << 20, 0);  // exact 2^-k
        r1 *= s; r2 *= s; r3 *= s; r4 *= s; a0 *= s;
        e2acc += k;
    }
    // tail: t = 1009..1023 (15 steps), frames already in slots 0..14
#pragma unroll
    for (int d = 0; d < 15; ++d)
        ctc_step((double)(f0[d] + EPSF), (double)(f1[d] + EPSF),
                 (double)(fB[d] + EPSF), k1, k3, a0, r1, r2, r3, r4);

    // loss = -( ln(A[255]+A[256]) + ln2 * e2acc ); states 255,256 = lane63 r3,r4
    if (l == 63) {
        double sum = r3 + r4;
        int hi = __double2hiint(sum), lo = __double2loint(sum);
        int e = (hi >> 20) - 1023;
        double mant = __hiloint2double((hi & 0x000FFFFF) | (1023 << 20), lo);
        double lg2 = (double)__log2f((float)mant) + (double)(e + e2acc);
        out[b] = (float)(-LN2D * lg2);
    }
}

extern "C" void kernel_launch(void* const* d_in, const int* in_sizes, int n_in,
                              void* d_out, int out_size, void* d_ws, size_t ws_size,
                              hipStream_t stream) {
    const int* y_true = (const int*)d_in[0];     // [256,128] int32
    const float* y_pred = (const float*)d_in[1]; // [256,1024,256] fp32
    float* out = (float*)d_out;                  // [256,1] fp32
    ctc_fwd<<<256, 64, 0, stream>>>(y_true, y_pred, out);
}